// Round 1
// baseline (1601.020 us; speedup 1.0000x reference)
//
#include <hip/hip_runtime.h>
#include <math.h>

#define Bc   8
#define Nc   2048
#define Mc   1024
#define Kc   64
#define Fc   64
#define C0c  67
#define C1c  64
#define C2c  128
#define NGRP (Bc*Mc)     /* 8192 */
#define R2c  0.04f
#define EPSc 1e-5f
#define NBLK 512
#define GPB  (NGRP/NBLK) /* 16 groups per block */

// numpy-matching squared distance: individually rounded mul/add, no FMA contraction
__device__ __forceinline__ float d2nf(float dx, float dy, float dz) {
  return __fadd_rn(__fadd_rn(__fmul_rn(dx,dx), __fmul_rn(dy,dy)), __fmul_rn(dz,dz));
}

// ---------------- Kernel 1: farthest point sampling (exact argmax semantics) ----------------
__global__ __launch_bounds__(256) void k_fps(const float* __restrict__ pos,
                                             int* __restrict__ idx_ws,
                                             int* __restrict__ cnt_total) {
  __shared__ float px[Nc], py[Nc], pz[Nc];
  __shared__ float sv[2][4];
  __shared__ int   si[2][4];
  const int b = blockIdx.x, t = threadIdx.x;
  if (b == 0 && t == 0) *cnt_total = 0;   // k_ball (next launch) atomically accumulates here
  const float* pb = pos + (size_t)b*Nc*3;
  for (int j = t; j < Nc; j += 256) { px[j]=pb[j*3+0]; py[j]=pb[j*3+1]; pz[j]=pb[j*3+2]; }
  __syncthreads();
  const int base = t*8;                    // contiguous chunk -> index-ordered tie-breaks
  float X[8],Y[8],Z[8],Mv[8];
  const float q0x=px[0], q0y=py[0], q0z=pz[0];
  float bv = -INFINITY; int bi = 0;
  #pragma unroll
  for (int i=0;i<8;i++){
    X[i]=px[base+i]; Y[i]=py[base+i]; Z[i]=pz[base+i];
    Mv[i] = d2nf(X[i]-q0x, Y[i]-q0y, Z[i]-q0z);
    if (Mv[i] > bv) { bv = Mv[i]; bi = base+i; }   // strict > keeps first max
  }
  if (t == 0) idx_ws[b*Mc] = 0;
  const int wid = t >> 6, lane = t & 63;
  for (int sel = 1; sel < Mc; sel++) {
    float v = bv; int idx = bi;
    #pragma unroll
    for (int off=1; off<64; off<<=1) {
      const float ov = __shfl_xor(v, off, 64);
      const int   oi = __shfl_xor(idx, off, 64);
      if (ov > v || (ov == v && oi < idx)) { v = ov; idx = oi; }
    }
    const int par = sel & 1;                // double-buffered 4-slot combine: 1 barrier/step
    if (lane == 0) { sv[par][wid] = v; si[par][wid] = idx; }
    __syncthreads();
    float fv = sv[par][0]; int fi = si[par][0];
    #pragma unroll
    for (int w=1; w<4; w++) {
      const float wv = sv[par][w]; const int wi = si[par][w];
      if (wv > fv || (wv == fv && wi < fi)) { fv = wv; fi = wi; }
    }
    if (t == 0) idx_ws[b*Mc + sel] = fi;
    const float qx = px[fi], qy = py[fi], qz = pz[fi];
    bv = -INFINITY; bi = 0;
    #pragma unroll
    for (int i=0;i<8;i++) {                 // fused min-update + next-step local argmax
      const float d = d2nf(X[i]-qx, Y[i]-qy, Z[i]-qz);
      Mv[i] = fminf(Mv[i], d);
      if (Mv[i] > bv) { bv = Mv[i]; bi = base+i; }
    }
  }
}

// ---------------- Kernel 2: ball query (first-K by index), writes pos/batch/idx outputs ----------------
__global__ __launch_bounds__(256) void k_ball(const float* __restrict__ pos,
                                              const int* __restrict__ idx_ws,
                                              int* __restrict__ nbr, int* __restrict__ cntarr,
                                              float* __restrict__ q_ws, int* __restrict__ cnt_total,
                                              float* __restrict__ out_pos, float* __restrict__ out_batch,
                                              float* __restrict__ out_idx) {
  __shared__ int sc[256];
  const int g = blockIdx.x, t = threadIdx.x;
  const int b = g >> 10;
  const int li = idx_ws[g];
  const float* pb = pos + (size_t)b*Nc*3;
  const float qx = pb[li*3+0], qy = pb[li*3+1], qz = pb[li*3+2];
  const int base = t*8;
  unsigned mask = 0;
  #pragma unroll
  for (int i=0;i<8;i++){
    const int j = base+i;
    const float d = d2nf(pb[j*3+0]-qx, pb[j*3+1]-qy, pb[j*3+2]-qz);
    if (d <= R2c) mask |= (1u<<i);
  }
  const int c = __popc(mask);
  sc[t] = c; __syncthreads();
  for (int off=1; off<256; off<<=1) {       // inclusive Hillis-Steele scan
    const int add = (t>=off) ? sc[t-off] : 0;
    __syncthreads();
    sc[t] += add;
    __syncthreads();
  }
  const int total = sc[255];
  int slot = sc[t] - c;                      // exclusive prefix
  #pragma unroll
  for (int i=0;i<8;i++){
    if (mask & (1u<<i)) {
      if (slot < Kc) nbr[(size_t)g*Kc + slot] = base+i;
      slot++;
    }
  }
  if (t == 0) {
    const int cv = total < Kc ? total : Kc;
    cntarr[g] = cv;
    atomicAdd(cnt_total, cv);
    q_ws[g*4+0]=qx; q_ws[g*4+1]=qy; q_ws[g*4+2]=qz;
    out_pos[g*3+0]=qx; out_pos[g*3+1]=qy; out_pos[g*3+2]=qz;
    out_batch[g] = (float)b;
    out_idx[g]   = (float)(b*Nc + li);
  }
}

// ---------------- Kernel 3: layer1 stats only (r1 recomputed later; no 134MB spill) ----------------
__global__ __launch_bounds__(256) void k_l1stats(const float* __restrict__ x, const float* __restrict__ pos,
                                                 const float* __restrict__ W1, const float* __restrict__ b1,
                                                 const int* __restrict__ nbr, const int* __restrict__ cntarr,
                                                 const float* __restrict__ q_ws,
                                                 float* __restrict__ p1sum, float* __restrict__ p1sq) {
  __shared__ __align__(16) float inb[Kc][68];
  __shared__ float sred[C1c], sqred[C1c];
  const int t = threadIdx.x;
  const int c0 = (t & 15) * 4, kg = t >> 4;    // thread computes k = kg*4+j, c = c0..c0+3
  const float4 b1q = *(const float4*)(b1 + c0);
  float ssum0=0,ssum1=0,ssum2=0,ssum3=0, ssq0=0,ssq1=0,ssq2=0,ssq3=0;
  const int gk = t >> 2, gq = t & 3;
  for (int gi = 0; gi < GPB; gi++) {
    const int g = blockIdx.x * GPB + gi;
    const int cnt = cntarr[g];
    const int b = g >> 10;
    {   // gather into LDS [64][68]
      float4* dst = (float4*)(&inb[gk][0]);
      if (gk < cnt) {
        const int idx = nbr[(size_t)g*Kc + gk];
        const float4* xr = (const float4*)(x + ((size_t)b*Nc + idx)*Fc);
        #pragma unroll
        for (int ii=0; ii<4; ii++) dst[gq*4+ii] = xr[gq*4+ii];
        if (gq == 0) {
          const float* pp = pos + ((size_t)b*Nc + idx)*3;
          inb[gk][64] = pp[0] - q_ws[g*4+0];
          inb[gk][65] = pp[1] - q_ws[g*4+1];
          inb[gk][66] = pp[2] - q_ws[g*4+2];
          inb[gk][67] = 0.f;
        }
      } else {
        const float4 z4 = make_float4(0.f,0.f,0.f,0.f);
        #pragma unroll
        for (int ii=0; ii<4; ii++) dst[gq*4+ii] = z4;
        if (gq == 0) { inb[gk][64]=0.f; inb[gk][65]=0.f; inb[gk][66]=0.f; inb[gk][67]=0.f; }
      }
    }
    __syncthreads();
    float acc[4][4];
    #pragma unroll
    for (int j=0;j<4;j++){acc[j][0]=0.f;acc[j][1]=0.f;acc[j][2]=0.f;acc[j][3]=0.f;}
    for (int cc=0; cc<C0c; cc++) {
      const float4 w = *(const float4*)(W1 + cc*C1c + c0);
      #pragma unroll
      for (int j=0;j<4;j++) {
        const float hv = inb[kg*4 + j][cc];
        acc[j][0] = fmaf(hv, w.x, acc[j][0]);
        acc[j][1] = fmaf(hv, w.y, acc[j][1]);
        acc[j][2] = fmaf(hv, w.z, acc[j][2]);
        acc[j][3] = fmaf(hv, w.w, acc[j][3]);
      }
    }
    #pragma unroll
    for (int j=0;j<4;j++) {
      const int k = kg*4 + j;
      if (k < cnt) {
        const float r0 = fmaxf(acc[j][0] + b1q.x, 0.f);
        const float r1 = fmaxf(acc[j][1] + b1q.y, 0.f);
        const float r2 = fmaxf(acc[j][2] + b1q.z, 0.f);
        const float r3 = fmaxf(acc[j][3] + b1q.w, 0.f);
        ssum0 += r0; ssq0 += r0*r0;
        ssum1 += r1; ssq1 += r1*r1;
        ssum2 += r2; ssq2 += r2*r2;
        ssum3 += r3; ssq3 += r3*r3;
      }
    }
    __syncthreads();
  }
  if (t < C1c) { sred[t]=0.f; sqred[t]=0.f; }
  __syncthreads();
  atomicAdd(&sred[c0+0], ssum0); atomicAdd(&sqred[c0+0], ssq0);
  atomicAdd(&sred[c0+1], ssum1); atomicAdd(&sqred[c0+1], ssq1);
  atomicAdd(&sred[c0+2], ssum2); atomicAdd(&sqred[c0+2], ssq2);
  atomicAdd(&sred[c0+3], ssum3); atomicAdd(&sqred[c0+3], ssq3);
  __syncthreads();
  if (t < C1c) { p1sum[(size_t)blockIdx.x*C1c + t] = sred[t]; p1sq[(size_t)blockIdx.x*C1c + t] = sqred[t]; }
}

// ---------------- finalize BN stats -> affine (a, c) ----------------
__global__ void k_fin(const float* __restrict__ psum, const float* __restrict__ psq,
                      const int* __restrict__ cnt_total,
                      const float* __restrict__ gam, const float* __restrict__ bet,
                      float* __restrict__ ac, int nch) {
  const int t = threadIdx.x;
  if (t >= nch) return;
  float s = 0.f, sq = 0.f;
  for (int p = 0; p < NBLK; p++) { s += psum[(size_t)p*nch + t]; sq += psq[(size_t)p*nch + t]; }
  const float cntf = (float)(*cnt_total);
  const float mean = s / cntf;
  const float var = fmaxf(sq / cntf - mean*mean, 0.f);
  const float a = gam[t] / sqrtf(var + EPSc);
  ac[t] = a;
  ac[nch + t] = bet[t] - mean * a;
}

// ---------------- Kernel 5: recompute r1, BN1-affine, layer2, masked max/min + stats2 ----------------
__global__ __launch_bounds__(256) void k_l2(const float* __restrict__ x, const float* __restrict__ pos,
                                            const float* __restrict__ W1, const float* __restrict__ b1,
                                            const float* __restrict__ W2, const float* __restrict__ b2,
                                            const int* __restrict__ nbr, const int* __restrict__ cntarr,
                                            const float* __restrict__ q_ws, const float* __restrict__ a1c,
                                            float* __restrict__ p2sum, float* __restrict__ p2sq,
                                            float* __restrict__ maxv, float* __restrict__ minv) {
  __shared__ __align__(16) float inb[Kc][68];
  __shared__ __align__(16) float h1b[Kc][68];
  __shared__ float redmax[8][C2c];
  __shared__ float redmin[8][C2c];
  __shared__ float sred[C2c], sqred[C2c];
  const int t = threadIdx.x;
  const int c0a = (t & 15) * 4, kga = t >> 4;   // phase A: k = kga*4+j
  const int c0b = (t & 31) * 4, kgb = t >> 5;   // phase B: k = kgb*8+j
  const float4 b1q = *(const float4*)(b1 + c0a);
  const float4 a1q = *(const float4*)(a1c + c0a);
  const float4 c1q = *(const float4*)(a1c + C1c + c0a);
  const float4 b2q = *(const float4*)(b2 + c0b);
  float ssum0=0,ssum1=0,ssum2=0,ssum3=0, ssq0=0,ssq1=0,ssq2=0,ssq3=0;
  const int gk = t >> 2, gq = t & 3;
  for (int gi = 0; gi < GPB; gi++) {
    const int g = blockIdx.x * GPB + gi;
    const int cnt = cntarr[g];
    const int b = g >> 10;
    {   // gather
      float4* dst = (float4*)(&inb[gk][0]);
      if (gk < cnt) {
        const int idx = nbr[(size_t)g*Kc + gk];
        const float4* xr = (const float4*)(x + ((size_t)b*Nc + idx)*Fc);
        #pragma unroll
        for (int ii=0; ii<4; ii++) dst[gq*4+ii] = xr[gq*4+ii];
        if (gq == 0) {
          const float* pp = pos + ((size_t)b*Nc + idx)*3;
          inb[gk][64] = pp[0] - q_ws[g*4+0];
          inb[gk][65] = pp[1] - q_ws[g*4+1];
          inb[gk][66] = pp[2] - q_ws[g*4+2];
          inb[gk][67] = 0.f;
        }
      } else {
        const float4 z4 = make_float4(0.f,0.f,0.f,0.f);
        #pragma unroll
        for (int ii=0; ii<4; ii++) dst[gq*4+ii] = z4;
        if (gq == 0) { inb[gk][64]=0.f; inb[gk][65]=0.f; inb[gk][66]=0.f; inb[gk][67]=0.f; }
      }
    }
    __syncthreads();
    {   // phase A: h1 = a1*relu(in@W1+b1)+c1 -> LDS
      float acc[4][4];
      #pragma unroll
      for (int j=0;j<4;j++){acc[j][0]=0.f;acc[j][1]=0.f;acc[j][2]=0.f;acc[j][3]=0.f;}
      for (int cc=0; cc<C0c; cc++) {
        const float4 w = *(const float4*)(W1 + cc*C1c + c0a);
        #pragma unroll
        for (int j=0;j<4;j++) {
          const float hv = inb[kga*4 + j][cc];
          acc[j][0] = fmaf(hv, w.x, acc[j][0]);
          acc[j][1] = fmaf(hv, w.y, acc[j][1]);
          acc[j][2] = fmaf(hv, w.z, acc[j][2]);
          acc[j][3] = fmaf(hv, w.w, acc[j][3]);
        }
      }
      #pragma unroll
      for (int j=0;j<4;j++) {
        const int k = kga*4 + j;
        float4 h;
        h.x = a1q.x * fmaxf(acc[j][0] + b1q.x, 0.f) + c1q.x;
        h.y = a1q.y * fmaxf(acc[j][1] + b1q.y, 0.f) + c1q.y;
        h.z = a1q.z * fmaxf(acc[j][2] + b1q.z, 0.f) + c1q.z;
        h.w = a1q.w * fmaxf(acc[j][3] + b1q.w, 0.f) + c1q.w;
        *(float4*)(&h1b[k][c0a]) = h;
      }
    }
    __syncthreads();
    {   // phase B: r2 = relu(h1@W2+b2); masked stats + max/min over k
      float acc[8][4];
      #pragma unroll
      for (int j=0;j<8;j++){acc[j][0]=0.f;acc[j][1]=0.f;acc[j][2]=0.f;acc[j][3]=0.f;}
      for (int cc=0; cc<C1c; cc++) {
        const float4 w = *(const float4*)(W2 + cc*C2c + c0b);
        #pragma unroll
        for (int j=0;j<8;j++) {
          const float hv = h1b[kgb*8 + j][cc];
          acc[j][0] = fmaf(hv, w.x, acc[j][0]);
          acc[j][1] = fmaf(hv, w.y, acc[j][1]);
          acc[j][2] = fmaf(hv, w.z, acc[j][2]);
          acc[j][3] = fmaf(hv, w.w, acc[j][3]);
        }
      }
      float lx0=-INFINITY,lx1=-INFINITY,lx2=-INFINITY,lx3=-INFINITY;
      float ln0= INFINITY,ln1= INFINITY,ln2= INFINITY,ln3= INFINITY;
      #pragma unroll
      for (int j=0;j<8;j++) {
        const int k = kgb*8 + j;
        if (k < cnt) {
          const float r0 = fmaxf(acc[j][0] + b2q.x, 0.f);
          const float r1 = fmaxf(acc[j][1] + b2q.y, 0.f);
          const float r2 = fmaxf(acc[j][2] + b2q.z, 0.f);
          const float r3 = fmaxf(acc[j][3] + b2q.w, 0.f);
          ssum0 += r0; ssq0 += r0*r0;
          ssum1 += r1; ssq1 += r1*r1;
          ssum2 += r2; ssq2 += r2*r2;
          ssum3 += r3; ssq3 += r3*r3;
          lx0 = fmaxf(lx0, r0); ln0 = fminf(ln0, r0);
          lx1 = fmaxf(lx1, r1); ln1 = fminf(ln1, r1);
          lx2 = fmaxf(lx2, r2); ln2 = fminf(ln2, r2);
          lx3 = fmaxf(lx3, r3); ln3 = fminf(ln3, r3);
        }
      }
      redmax[kgb][c0b+0]=lx0; redmax[kgb][c0b+1]=lx1; redmax[kgb][c0b+2]=lx2; redmax[kgb][c0b+3]=lx3;
      redmin[kgb][c0b+0]=ln0; redmin[kgb][c0b+1]=ln1; redmin[kgb][c0b+2]=ln2; redmin[kgb][c0b+3]=ln3;
    }
    __syncthreads();
    if (t < C2c) {
      float mx = redmax[0][t], mn = redmin[0][t];
      #pragma unroll
      for (int w=1; w<8; w++) { mx = fmaxf(mx, redmax[w][t]); mn = fminf(mn, redmin[w][t]); }
      maxv[(size_t)g*C2c + t] = mx;
      minv[(size_t)g*C2c + t] = mn;
    }
    __syncthreads();
  }
  if (t < C2c) { sred[t] = 0.f; sqred[t] = 0.f; }
  __syncthreads();
  atomicAdd(&sred[c0b+0], ssum0); atomicAdd(&sqred[c0b+0], ssq0);
  atomicAdd(&sred[c0b+1], ssum1); atomicAdd(&sqred[c0b+1], ssq1);
  atomicAdd(&sred[c0b+2], ssum2); atomicAdd(&sqred[c0b+2], ssq2);
  atomicAdd(&sred[c0b+3], ssum3); atomicAdd(&sqred[c0b+3], ssq3);
  __syncthreads();
  if (t < C2c) { p2sum[(size_t)blockIdx.x*C2c + t] = sred[t]; p2sq[(size_t)blockIdx.x*C2c + t] = sqred[t]; }
}

// ---------------- Kernel 7: x_out = a2*extreme + c2 (BN2 commutes with masked max) ----------------
__global__ __launch_bounds__(256) void k_out(const float* __restrict__ maxv, const float* __restrict__ minv,
                                             const float* __restrict__ a2c, float* __restrict__ xout) {
  const int i = blockIdx.x*256 + threadIdx.x;
  const int c = i & (C2c-1);
  const float a = a2c[c], cc = a2c[C2c + c];
  const float v = (a >= 0.f) ? maxv[i] : minv[i];
  xout[i] = a * v + cc;
}

extern "C" void kernel_launch(void* const* d_in, const int* in_sizes, int n_in,
                              void* d_out, int out_size, void* d_ws, size_t ws_size,
                              hipStream_t stream) {
  (void)in_sizes; (void)n_in; (void)out_size; (void)ws_size;
  const float* x   = (const float*)d_in[0];
  const float* pos = (const float*)d_in[1];
  const float* W1  = (const float*)d_in[3];
  const float* b1  = (const float*)d_in[4];
  const float* g1  = (const float*)d_in[5];
  const float* be1 = (const float*)d_in[6];
  const float* W2  = (const float*)d_in[7];
  const float* b2  = (const float*)d_in[8];
  const float* g2  = (const float*)d_in[9];
  const float* be2 = (const float*)d_in[10];

  char* ws = (char*)d_ws;                      // ~11.5 MB total
  int*   idx_ws    = (int*)  (ws + 0);         // [8192]
  int*   cntarr    = (int*)  (ws + 32768);     // [8192]
  int*   nbr       = (int*)  (ws + 65536);     // [8192*64]
  float* q_ws      = (float*)(ws + 2162688);   // [8192*4]
  int*   cnt_total = (int*)  (ws + 2293760);
  float* p1sum     = (float*)(ws + 2294016);   // [512*64]
  float* p1sq      = (float*)(ws + 2425088);
  float* p2sum     = (float*)(ws + 2556160);   // [512*128]
  float* p2sq      = (float*)(ws + 2818304);
  float* a1c       = (float*)(ws + 3080448);   // [128]
  float* a2c       = (float*)(ws + 3080960);   // [256]
  float* maxv      = (float*)(ws + 3081984);   // [8192*128]
  float* minv      = (float*)(ws + 7276288);   // [8192*128]

  float* xout      = (float*)d_out;            // [8192*128]
  float* out_pos   = xout + (size_t)NGRP*C2c;  // [8192*3]
  float* out_batch = out_pos + (size_t)NGRP*3; // [8192]
  float* out_idx   = out_batch + NGRP;         // [8192]

  k_fps<<<Bc, 256, 0, stream>>>(pos, idx_ws, cnt_total);
  k_ball<<<NGRP, 256, 0, stream>>>(pos, idx_ws, nbr, cntarr, q_ws, cnt_total,
                                   out_pos, out_batch, out_idx);
  k_l1stats<<<NBLK, 256, 0, stream>>>(x, pos, W1, b1, nbr, cntarr, q_ws, p1sum, p1sq);
  k_fin<<<1, C1c, 0, stream>>>(p1sum, p1sq, cnt_total, g1, be1, a1c, C1c);
  k_l2<<<NBLK, 256, 0, stream>>>(x, pos, W1, b1, W2, b2, nbr, cntarr, q_ws, a1c,
                                 p2sum, p2sq, maxv, minv);
  k_fin<<<1, C2c, 0, stream>>>(p2sum, p2sq, cnt_total, g2, be2, a2c, C2c);
  k_out<<<(NGRP*C2c)/256, 256, 0, stream>>>(maxv, minv, a2c, xout);
}

// Round 2
// 1183.371 us; speedup vs baseline: 1.3529x; 1.3529x over previous
//
#include <hip/hip_runtime.h>
#include <math.h>

#define Bc   8
#define Nc   2048
#define Mc   1024
#define Kc   64
#define Fc   64
#define C0c  67
#define C1c  64
#define C2c  128
#define NGRP (Bc*Mc)     /* 8192 */
#define R2c  0.04f
#define EPSc 1e-5f
#define NBLK 512
#define GPB  (NGRP/NBLK) /* 16 groups per block */

// numpy-matching squared distance: individually rounded mul/add, no FMA contraction
__device__ __forceinline__ float d2nf(float dx, float dy, float dz) {
  return __fadd_rn(__fadd_rn(__fmul_rn(dx,dx), __fmul_rn(dy,dy)), __fmul_rn(dz,dz));
}

// ---------------- Kernel 1: farthest point sampling (exact argmax semantics) ----------------
// Key design rules (round 1 post-mortem): NO global memory op inside the serial
// 1023-step loop (the compiler drains vmcnt(0) before every s_barrier -> ~HBM
// round trip per step). Indices buffered in LDS, flushed once at the end.
__global__ __launch_bounds__(256) void k_fps(const float* __restrict__ pos,
                                             int* __restrict__ idx_ws,
                                             int* __restrict__ cnt_total) {
  __shared__ __align__(16) float4 pq[Nc];      // 32 KB: coords as float4 -> 1 ds_read_b128
  __shared__ int sidx[Mc];                     // 4 KB: selected indices, flushed at end
  __shared__ __align__(16) float svf[2][8];    // [par][0..3]=wave max, [4..7]=wave idx (bits)
  const int b = blockIdx.x, t = threadIdx.x;
  if (b == 0 && t == 0) *cnt_total = 0;        // k_ball (next launch) accumulates here
  const float* pb = pos + (size_t)b*Nc*3;
  for (int j = t; j < Nc; j += 256)
    pq[j] = make_float4(pb[j*3+0], pb[j*3+1], pb[j*3+2], 0.f);
  __syncthreads();
  const int base = t*8;                        // contiguous chunk -> monotonic tie-break order
  float X[8],Y[8],Z[8],Mv[8];
  const float q0x=pq[0].x, q0y=pq[0].y, q0z=pq[0].z;
  float m = -INFINITY;                         // local (per-thread) running max of Mv
  #pragma unroll
  for (int i=0;i<8;i++){
    const float4 p = pq[base+i];
    X[i]=p.x; Y[i]=p.y; Z[i]=p.z;
    Mv[i] = d2nf(X[i]-q0x, Y[i]-q0y, Z[i]-q0z);
    m = fmaxf(m, Mv[i]);
  }
  if (t == 0) sidx[0] = 0;
  const int wid = t >> 6, lane = t & 63;
  for (int sel = 1; sel < Mc; sel++) {
    // ---- value-only wave max butterfly (6 fmax + 6 bpermute) ----
    float v = m;
    #pragma unroll
    for (int off=1; off<64; off<<=1) v = fmaxf(v, __shfl_xor(v, off, 64));
    // ---- resolve this wave's first index achieving v ----
    const unsigned long long bal = __ballot(m == v);
    const int l0 = __ffsll(bal) - 1;           // first lane with the wave max
    int fpos = 7;
    #pragma unroll
    for (int i=6;i>=0;i--) fpos = (Mv[i]==v) ? i : fpos;  // first slot (valid on winner lane)
    const int widx = __shfl(base + fpos, l0, 64);
    const int par = sel & 1;                   // double-buffered slots: 1 barrier/step
    if (lane == 0) { svf[par][wid] = v; svf[par][4+wid] = __int_as_float(widx); }
    __syncthreads();
    const float4 va = *(const float4*)&svf[par][0];
    const float4 vb = *(const float4*)&svf[par][4];
    const float bm = fmaxf(fmaxf(va.x,va.y), fmaxf(va.z,va.w));
    int fi = __float_as_int(vb.w);             // descending chain -> lowest wave wins ties
    if (va.z == bm) fi = __float_as_int(vb.z);
    if (va.y == bm) fi = __float_as_int(vb.y);
    if (va.x == bm) fi = __float_as_int(vb.x);
    if (t == 0) sidx[sel] = fi;
    const float4 q = pq[fi];                   // single broadcast ds_read_b128
    // ---- fused min-update + local max ----
    m = -INFINITY;
    #pragma unroll
    for (int i=0;i<8;i++) {
      const float d = d2nf(X[i]-q.x, Y[i]-q.y, Z[i]-q.z);
      Mv[i] = fminf(Mv[i], d);
      m = fmaxf(m, Mv[i]);
    }
  }
  __syncthreads();
  for (int j = t; j < Mc; j += 256) idx_ws[b*Mc + j] = sidx[j];  // one coalesced flush
}

// ---------------- Kernel 2: ball query (first-K by index), writes pos/batch/idx outputs ----------------
__global__ __launch_bounds__(256) void k_ball(const float* __restrict__ pos,
                                              const int* __restrict__ idx_ws,
                                              int* __restrict__ nbr, int* __restrict__ cntarr,
                                              float* __restrict__ q_ws, int* __restrict__ cnt_total,
                                              float* __restrict__ out_pos, float* __restrict__ out_batch,
                                              float* __restrict__ out_idx) {
  __shared__ int sc[256];
  const int g = blockIdx.x, t = threadIdx.x;
  const int b = g >> 10;
  const int li = idx_ws[g];
  const float* pb = pos + (size_t)b*Nc*3;
  const float qx = pb[li*3+0], qy = pb[li*3+1], qz = pb[li*3+2];
  const int base = t*8;
  unsigned mask = 0;
  #pragma unroll
  for (int i=0;i<8;i++){
    const int j = base+i;
    const float d = d2nf(pb[j*3+0]-qx, pb[j*3+1]-qy, pb[j*3+2]-qz);
    if (d <= R2c) mask |= (1u<<i);
  }
  const int c = __popc(mask);
  sc[t] = c; __syncthreads();
  for (int off=1; off<256; off<<=1) {       // inclusive Hillis-Steele scan
    const int add = (t>=off) ? sc[t-off] : 0;
    __syncthreads();
    sc[t] += add;
    __syncthreads();
  }
  const int total = sc[255];
  int slot = sc[t] - c;                      // exclusive prefix
  #pragma unroll
  for (int i=0;i<8;i++){
    if (mask & (1u<<i)) {
      if (slot < Kc) nbr[(size_t)g*Kc + slot] = base+i;
      slot++;
    }
  }
  if (t == 0) {
    const int cv = total < Kc ? total : Kc;
    cntarr[g] = cv;
    atomicAdd(cnt_total, cv);
    q_ws[g*4+0]=qx; q_ws[g*4+1]=qy; q_ws[g*4+2]=qz;
    out_pos[g*3+0]=qx; out_pos[g*3+1]=qy; out_pos[g*3+2]=qz;
    out_batch[g] = (float)b;
    out_idx[g]   = (float)(b*Nc + li);
  }
}

// ---------------- Kernel 3: layer1 stats only (r1 recomputed later; no 134MB spill) ----------------
__global__ __launch_bounds__(256) void k_l1stats(const float* __restrict__ x, const float* __restrict__ pos,
                                                 const float* __restrict__ W1, const float* __restrict__ b1,
                                                 const int* __restrict__ nbr, const int* __restrict__ cntarr,
                                                 const float* __restrict__ q_ws,
                                                 float* __restrict__ p1sum, float* __restrict__ p1sq) {
  __shared__ __align__(16) float inb[Kc][68];
  __shared__ float sred[C1c], sqred[C1c];
  const int t = threadIdx.x;
  const int c0 = (t & 15) * 4, kg = t >> 4;    // thread computes k = kg*4+j, c = c0..c0+3
  const float4 b1q = *(const float4*)(b1 + c0);
  float ssum0=0,ssum1=0,ssum2=0,ssum3=0, ssq0=0,ssq1=0,ssq2=0,ssq3=0;
  const int gk = t >> 2, gq = t & 3;
  for (int gi = 0; gi < GPB; gi++) {
    const int g = blockIdx.x * GPB + gi;
    const int cnt = cntarr[g];
    const int b = g >> 10;
    {   // gather into LDS [64][68]
      float4* dst = (float4*)(&inb[gk][0]);
      if (gk < cnt) {
        const int idx = nbr[(size_t)g*Kc + gk];
        const float4* xr = (const float4*)(x + ((size_t)b*Nc + idx)*Fc);
        #pragma unroll
        for (int ii=0; ii<4; ii++) dst[gq*4+ii] = xr[gq*4+ii];
        if (gq == 0) {
          const float* pp = pos + ((size_t)b*Nc + idx)*3;
          inb[gk][64] = pp[0] - q_ws[g*4+0];
          inb[gk][65] = pp[1] - q_ws[g*4+1];
          inb[gk][66] = pp[2] - q_ws[g*4+2];
          inb[gk][67] = 0.f;
        }
      } else {
        const float4 z4 = make_float4(0.f,0.f,0.f,0.f);
        #pragma unroll
        for (int ii=0; ii<4; ii++) dst[gq*4+ii] = z4;
        if (gq == 0) { inb[gk][64]=0.f; inb[gk][65]=0.f; inb[gk][66]=0.f; inb[gk][67]=0.f; }
      }
    }
    __syncthreads();
    float acc[4][4];
    #pragma unroll
    for (int j=0;j<4;j++){acc[j][0]=0.f;acc[j][1]=0.f;acc[j][2]=0.f;acc[j][3]=0.f;}
    for (int cc=0; cc<C0c; cc++) {
      const float4 w = *(const float4*)(W1 + cc*C1c + c0);
      #pragma unroll
      for (int j=0;j<4;j++) {
        const float hv = inb[kg*4 + j][cc];
        acc[j][0] = fmaf(hv, w.x, acc[j][0]);
        acc[j][1] = fmaf(hv, w.y, acc[j][1]);
        acc[j][2] = fmaf(hv, w.z, acc[j][2]);
        acc[j][3] = fmaf(hv, w.w, acc[j][3]);
      }
    }
    #pragma unroll
    for (int j=0;j<4;j++) {
      const int k = kg*4 + j;
      if (k < cnt) {
        const float r0 = fmaxf(acc[j][0] + b1q.x, 0.f);
        const float r1 = fmaxf(acc[j][1] + b1q.y, 0.f);
        const float r2 = fmaxf(acc[j][2] + b1q.z, 0.f);
        const float r3 = fmaxf(acc[j][3] + b1q.w, 0.f);
        ssum0 += r0; ssq0 += r0*r0;
        ssum1 += r1; ssq1 += r1*r1;
        ssum2 += r2; ssq2 += r2*r2;
        ssum3 += r3; ssq3 += r3*r3;
      }
    }
    __syncthreads();
  }
  if (t < C1c) { sred[t]=0.f; sqred[t]=0.f; }
  __syncthreads();
  atomicAdd(&sred[c0+0], ssum0); atomicAdd(&sqred[c0+0], ssq0);
  atomicAdd(&sred[c0+1], ssum1); atomicAdd(&sqred[c0+1], ssq1);
  atomicAdd(&sred[c0+2], ssum2); atomicAdd(&sqred[c0+2], ssq2);
  atomicAdd(&sred[c0+3], ssum3); atomicAdd(&sqred[c0+3], ssq3);
  __syncthreads();
  if (t < C1c) { p1sum[(size_t)blockIdx.x*C1c + t] = sred[t]; p1sq[(size_t)blockIdx.x*C1c + t] = sqred[t]; }
}

// ---------------- finalize BN stats -> affine (a, c) ----------------
__global__ void k_fin(const float* __restrict__ psum, const float* __restrict__ psq,
                      const int* __restrict__ cnt_total,
                      const float* __restrict__ gam, const float* __restrict__ bet,
                      float* __restrict__ ac, int nch) {
  const int t = threadIdx.x;
  if (t >= nch) return;
  float s = 0.f, sq = 0.f;
  for (int p = 0; p < NBLK; p++) { s += psum[(size_t)p*nch + t]; sq += psq[(size_t)p*nch + t]; }
  const float cntf = (float)(*cnt_total);
  const float mean = s / cntf;
  const float var = fmaxf(sq / cntf - mean*mean, 0.f);
  const float a = gam[t] / sqrtf(var + EPSc);
  ac[t] = a;
  ac[nch + t] = bet[t] - mean * a;
}

// ---------------- Kernel 5: recompute r1, BN1-affine, layer2, masked max/min + stats2 ----------------
__global__ __launch_bounds__(256) void k_l2(const float* __restrict__ x, const float* __restrict__ pos,
                                            const float* __restrict__ W1, const float* __restrict__ b1,
                                            const float* __restrict__ W2, const float* __restrict__ b2,
                                            const int* __restrict__ nbr, const int* __restrict__ cntarr,
                                            const float* __restrict__ q_ws, const float* __restrict__ a1c,
                                            float* __restrict__ p2sum, float* __restrict__ p2sq,
                                            float* __restrict__ maxv, float* __restrict__ minv) {
  __shared__ __align__(16) float inb[Kc][68];
  __shared__ __align__(16) float h1b[Kc][68];
  __shared__ float redmax[8][C2c];
  __shared__ float redmin[8][C2c];
  __shared__ float sred[C2c], sqred[C2c];
  const int t = threadIdx.x;
  const int c0a = (t & 15) * 4, kga = t >> 4;   // phase A: k = kga*4+j
  const int c0b = (t & 31) * 4, kgb = t >> 5;   // phase B: k = kgb*8+j
  const float4 b1q = *(const float4*)(b1 + c0a);
  const float4 a1q = *(const float4*)(a1c + c0a);
  const float4 c1q = *(const float4*)(a1c + C1c + c0a);
  const float4 b2q = *(const float4*)(b2 + c0b);
  float ssum0=0,ssum1=0,ssum2=0,ssum3=0, ssq0=0,ssq1=0,ssq2=0,ssq3=0;
  const int gk = t >> 2, gq = t & 3;
  for (int gi = 0; gi < GPB; gi++) {
    const int g = blockIdx.x * GPB + gi;
    const int cnt = cntarr[g];
    const int b = g >> 10;
    {   // gather
      float4* dst = (float4*)(&inb[gk][0]);
      if (gk < cnt) {
        const int idx = nbr[(size_t)g*Kc + gk];
        const float4* xr = (const float4*)(x + ((size_t)b*Nc + idx)*Fc);
        #pragma unroll
        for (int ii=0; ii<4; ii++) dst[gq*4+ii] = xr[gq*4+ii];
        if (gq == 0) {
          const float* pp = pos + ((size_t)b*Nc + idx)*3;
          inb[gk][64] = pp[0] - q_ws[g*4+0];
          inb[gk][65] = pp[1] - q_ws[g*4+1];
          inb[gk][66] = pp[2] - q_ws[g*4+2];
          inb[gk][67] = 0.f;
        }
      } else {
        const float4 z4 = make_float4(0.f,0.f,0.f,0.f);
        #pragma unroll
        for (int ii=0; ii<4; ii++) dst[gq*4+ii] = z4;
        if (gq == 0) { inb[gk][64]=0.f; inb[gk][65]=0.f; inb[gk][66]=0.f; inb[gk][67]=0.f; }
      }
    }
    __syncthreads();
    {   // phase A: h1 = a1*relu(in@W1+b1)+c1 -> LDS
      float acc[4][4];
      #pragma unroll
      for (int j=0;j<4;j++){acc[j][0]=0.f;acc[j][1]=0.f;acc[j][2]=0.f;acc[j][3]=0.f;}
      for (int cc=0; cc<C0c; cc++) {
        const float4 w = *(const float4*)(W1 + cc*C1c + c0a);
        #pragma unroll
        for (int j=0;j<4;j++) {
          const float hv = inb[kga*4 + j][cc];
          acc[j][0] = fmaf(hv, w.x, acc[j][0]);
          acc[j][1] = fmaf(hv, w.y, acc[j][1]);
          acc[j][2] = fmaf(hv, w.z, acc[j][2]);
          acc[j][3] = fmaf(hv, w.w, acc[j][3]);
        }
      }
      #pragma unroll
      for (int j=0;j<4;j++) {
        const int k = kga*4 + j;
        float4 h;
        h.x = a1q.x * fmaxf(acc[j][0] + b1q.x, 0.f) + c1q.x;
        h.y = a1q.y * fmaxf(acc[j][1] + b1q.y, 0.f) + c1q.y;
        h.z = a1q.z * fmaxf(acc[j][2] + b1q.z, 0.f) + c1q.z;
        h.w = a1q.w * fmaxf(acc[j][3] + b1q.w, 0.f) + c1q.w;
        *(float4*)(&h1b[k][c0a]) = h;
      }
    }
    __syncthreads();
    {   // phase B: r2 = relu(h1@W2+b2); masked stats + max/min over k
      float acc[8][4];
      #pragma unroll
      for (int j=0;j<8;j++){acc[j][0]=0.f;acc[j][1]=0.f;acc[j][2]=0.f;acc[j][3]=0.f;}
      for (int cc=0; cc<C1c; cc++) {
        const float4 w = *(const float4*)(W2 + cc*C2c + c0b);
        #pragma unroll
        for (int j=0;j<8;j++) {
          const float hv = h1b[kgb*8 + j][cc];
          acc[j][0] = fmaf(hv, w.x, acc[j][0]);
          acc[j][1] = fmaf(hv, w.y, acc[j][1]);
          acc[j][2] = fmaf(hv, w.z, acc[j][2]);
          acc[j][3] = fmaf(hv, w.w, acc[j][3]);
        }
      }
      float lx0=-INFINITY,lx1=-INFINITY,lx2=-INFINITY,lx3=-INFINITY;
      float ln0= INFINITY,ln1= INFINITY,ln2= INFINITY,ln3= INFINITY;
      #pragma unroll
      for (int j=0;j<8;j++) {
        const int k = kgb*8 + j;
        if (k < cnt) {
          const float r0 = fmaxf(acc[j][0] + b2q.x, 0.f);
          const float r1 = fmaxf(acc[j][1] + b2q.y, 0.f);
          const float r2 = fmaxf(acc[j][2] + b2q.z, 0.f);
          const float r3 = fmaxf(acc[j][3] + b2q.w, 0.f);
          ssum0 += r0; ssq0 += r0*r0;
          ssum1 += r1; ssq1 += r1*r1;
          ssum2 += r2; ssq2 += r2*r2;
          ssum3 += r3; ssq3 += r3*r3;
          lx0 = fmaxf(lx0, r0); ln0 = fminf(ln0, r0);
          lx1 = fmaxf(lx1, r1); ln1 = fminf(ln1, r1);
          lx2 = fmaxf(lx2, r2); ln2 = fminf(ln2, r2);
          lx3 = fmaxf(lx3, r3); ln3 = fminf(ln3, r3);
        }
      }
      redmax[kgb][c0b+0]=lx0; redmax[kgb][c0b+1]=lx1; redmax[kgb][c0b+2]=lx2; redmax[kgb][c0b+3]=lx3;
      redmin[kgb][c0b+0]=ln0; redmin[kgb][c0b+1]=ln1; redmin[kgb][c0b+2]=ln2; redmin[kgb][c0b+3]=ln3;
    }
    __syncthreads();
    if (t < C2c) {
      float mx = redmax[0][t], mn = redmin[0][t];
      #pragma unroll
      for (int w=1; w<8; w++) { mx = fmaxf(mx, redmax[w][t]); mn = fminf(mn, redmin[w][t]); }
      maxv[(size_t)g*C2c + t] = mx;
      minv[(size_t)g*C2c + t] = mn;
    }
    __syncthreads();
  }
  if (t < C2c) { sred[t] = 0.f; sqred[t] = 0.f; }
  __syncthreads();
  atomicAdd(&sred[c0b+0], ssum0); atomicAdd(&sqred[c0b+0], ssq0);
  atomicAdd(&sred[c0b+1], ssum1); atomicAdd(&sqred[c0b+1], ssq1);
  atomicAdd(&sred[c0b+2], ssum2); atomicAdd(&sqred[c0b+2], ssq2);
  atomicAdd(&sred[c0b+3], ssum3); atomicAdd(&sqred[c0b+3], ssq3);
  __syncthreads();
  if (t < C2c) { p2sum[(size_t)blockIdx.x*C2c + t] = sred[t]; p2sq[(size_t)blockIdx.x*C2c + t] = sqred[t]; }
}

// ---------------- Kernel 7: x_out = a2*extreme + c2 (BN2 commutes with masked max) ----------------
__global__ __launch_bounds__(256) void k_out(const float* __restrict__ maxv, const float* __restrict__ minv,
                                             const float* __restrict__ a2c, float* __restrict__ xout) {
  const int i = blockIdx.x*256 + threadIdx.x;
  const int c = i & (C2c-1);
  const float a = a2c[c], cc = a2c[C2c + c];
  const float v = (a >= 0.f) ? maxv[i] : minv[i];
  xout[i] = a * v + cc;
}

extern "C" void kernel_launch(void* const* d_in, const int* in_sizes, int n_in,
                              void* d_out, int out_size, void* d_ws, size_t ws_size,
                              hipStream_t stream) {
  (void)in_sizes; (void)n_in; (void)out_size; (void)ws_size;
  const float* x   = (const float*)d_in[0];
  const float* pos = (const float*)d_in[1];
  const float* W1  = (const float*)d_in[3];
  const float* b1  = (const float*)d_in[4];
  const float* g1  = (const float*)d_in[5];
  const float* be1 = (const float*)d_in[6];
  const float* W2  = (const float*)d_in[7];
  const float* b2  = (const float*)d_in[8];
  const float* g2  = (const float*)d_in[9];
  const float* be2 = (const float*)d_in[10];

  char* ws = (char*)d_ws;                      // ~11.5 MB total
  int*   idx_ws    = (int*)  (ws + 0);         // [8192]
  int*   cntarr    = (int*)  (ws + 32768);     // [8192]
  int*   nbr       = (int*)  (ws + 65536);     // [8192*64]
  float* q_ws      = (float*)(ws + 2162688);   // [8192*4]
  int*   cnt_total = (int*)  (ws + 2293760);
  float* p1sum     = (float*)(ws + 2294016);   // [512*64]
  float* p1sq      = (float*)(ws + 2425088);
  float* p2sum     = (float*)(ws + 2556160);   // [512*128]
  float* p2sq      = (float*)(ws + 2818304);
  float* a1c       = (float*)(ws + 3080448);   // [128]
  float* a2c       = (float*)(ws + 3080960);   // [256]
  float* maxv      = (float*)(ws + 3081984);   // [8192*128]
  float* minv      = (float*)(ws + 7276288);   // [8192*128]

  float* xout      = (float*)d_out;            // [8192*128]
  float* out_pos   = xout + (size_t)NGRP*C2c;  // [8192*3]
  float* out_batch = out_pos + (size_t)NGRP*3; // [8192]
  float* out_idx   = out_batch + NGRP;         // [8192]

  k_fps<<<Bc, 256, 0, stream>>>(pos, idx_ws, cnt_total);
  k_ball<<<NGRP, 256, 0, stream>>>(pos, idx_ws, nbr, cntarr, q_ws, cnt_total,
                                   out_pos, out_batch, out_idx);
  k_l1stats<<<NBLK, 256, 0, stream>>>(x, pos, W1, b1, nbr, cntarr, q_ws, p1sum, p1sq);
  k_fin<<<1, C1c, 0, stream>>>(p1sum, p1sq, cnt_total, g1, be1, a1c, C1c);
  k_l2<<<NBLK, 256, 0, stream>>>(x, pos, W1, b1, W2, b2, nbr, cntarr, q_ws, a1c,
                                 p2sum, p2sq, maxv, minv);
  k_fin<<<1, C2c, 0, stream>>>(p2sum, p2sq, cnt_total, g2, be2, a2c, C2c);
  k_out<<<(NGRP*C2c)/256, 256, 0, stream>>>(maxv, minv, a2c, xout);
}

// Round 4
// 1145.288 us; speedup vs baseline: 1.3979x; 1.0333x over previous
//
#include <hip/hip_runtime.h>
#include <math.h>

#define Bc   8
#define Nc   2048
#define Mc   1024
#define Kc   64
#define Fc   64
#define C0c  67
#define C1c  64
#define C2c  128
#define NGRP (Bc*Mc)     /* 8192 */
#define R2c  0.04f
#define EPSc 1e-5f
#define NBLK 512
#define GPB  (NGRP/NBLK) /* 16 groups per block */

// numpy-matching squared distance: individually rounded mul/add, no FMA contraction
__device__ __forceinline__ float d2nf(float dx, float dy, float dz) {
  return __fadd_rn(__fadd_rn(__fmul_rn(dx,dx), __fmul_rn(dy,dy)), __fmul_rn(dz,dz));
}

// ---- DPP wave64 max reduction (VALU latency, NOT LDS-crossbar like shfl) ----
// MAX is idempotent -> full row/bank masks are safe (unlike SUM, which needs
// row_mask 0xa/0xc on the bcast steps — that bug crashed round 3's k_ball).
// bound_ctrl=1 zero-fill is identity-safe: inputs are squared distances >= 0.
template<int CTRL>
__device__ __forceinline__ float dpp_maxf(float x) {
  const int o = __builtin_amdgcn_update_dpp(0, __float_as_int(x), CTRL, 0xf, 0xf, true);
  return fmaxf(x, __int_as_float(o));
}
__device__ __forceinline__ float wave_max64(float x) {
  x = dpp_maxf<0x111>(x);   // row_shr:1
  x = dpp_maxf<0x112>(x);   // row_shr:2
  x = dpp_maxf<0x114>(x);   // row_shr:4
  x = dpp_maxf<0x118>(x);   // row_shr:8  -> lane15/31/47/63 hold row maxes
  x = dpp_maxf<0x142>(x);   // row_bcast:15
  x = dpp_maxf<0x143>(x);   // row_bcast:31 -> lane63 = full 64-lane max
  return __int_as_float(__builtin_amdgcn_readlane(__float_as_int(x), 63));
}

// ---------------- Kernel 1: farthest point sampling (exact argmax semantics) ----------------
// Round-1 lesson: no global mem ops in the serial loop (vmcnt(0) drain before s_barrier).
// Round-2 lesson: shfl butterfly = 6 dependent LDS-crossbar hops; replaced with DPP.
// Winner's coords travel through the combine slots -> only ONE LDS round-trip per step.
__global__ __launch_bounds__(256) void k_fps(const float* __restrict__ pos,
                                             int* __restrict__ idx_ws,
                                             int* __restrict__ cnt_total) {
  __shared__ int sidx[Mc];                       // selected indices, flushed once at end
  __shared__ __align__(16) float sV[2][4];       // per-wave winner value
  __shared__ __align__(16) float sI[2][4];       // per-wave winner index (bits)
  __shared__ __align__(16) float sX[2][4];       // per-wave winner coords
  __shared__ __align__(16) float sY[2][4];
  __shared__ __align__(16) float sZ[2][4];
  const int b = blockIdx.x, t = threadIdx.x;
  if (b == 0 && t == 0) *cnt_total = 0;          // k_ball (next launch) accumulates here
  const float* pb = pos + (size_t)b*Nc*3;
  const int base = t*8;                          // contiguous chunk -> monotonic tie-break
  float X[8],Y[8],Z[8],Mv[8];
  {   // 24 floats/thread, 16B-aligned (96B stride) -> 6 float4 loads
    float4 buf[6];
    const float4* src = (const float4*)(pb + (size_t)base*3);
    #pragma unroll
    for (int ii=0; ii<6; ii++) buf[ii] = src[ii];
    const float* pf = (const float*)buf;
    #pragma unroll
    for (int i=0;i<8;i++){ X[i]=pf[i*3+0]; Y[i]=pf[i*3+1]; Z[i]=pf[i*3+2]; }
  }
  const float q0x=pb[0], q0y=pb[1], q0z=pb[2];
  float m = -INFINITY;
  #pragma unroll
  for (int i=0;i<8;i++){
    Mv[i] = d2nf(X[i]-q0x, Y[i]-q0y, Z[i]-q0z);
    m = fmaxf(m, Mv[i]);
  }
  if (t == 0) sidx[0] = 0;
  const int wid = t >> 6, lane = t & 63;
  for (int sel = 1; sel < Mc; sel++) {
    const float v = wave_max64(m);               // uniform wave max, VALU-latency chain
    const unsigned long long bal = __ballot(m == v);
    const int l0 = __ffsll(bal) - 1;             // first lane holding the wave max
    // first slot + its coords (meaningful on winner lane only)
    int fpos = 7;
    #pragma unroll
    for (int i=6;i>=0;i--) fpos = (Mv[i]==v) ? i : fpos;
    float sx=X[7], sy=Y[7], sz=Z[7];
    #pragma unroll
    for (int i=6;i>=0;i--){ const bool p=(Mv[i]==v); sx=p?X[i]:sx; sy=p?Y[i]:sy; sz=p?Z[i]:sz; }
    const int par = sel & 1;                     // double-buffered slots: 1 barrier/step
    if (lane == l0) {
      sV[par][wid] = v;
      sI[par][wid] = __int_as_float(base + fpos);
      sX[par][wid] = sx; sY[par][wid] = sy; sZ[par][wid] = sz;
    }
    __syncthreads();
    const float4 Vv = *(const float4*)sV[par];
    const float4 Iv = *(const float4*)sI[par];
    const float4 Xv = *(const float4*)sX[par];
    const float4 Yv = *(const float4*)sY[par];
    const float4 Zv = *(const float4*)sZ[par];
    const float bm = fmaxf(fmaxf(Vv.x,Vv.y), fmaxf(Vv.z,Vv.w));
    int fi = __float_as_int(Iv.w);               // descending chain -> lowest wave wins ties
    float nqx=Xv.w, nqy=Yv.w, nqz=Zv.w;
    if (Vv.z == bm) { fi=__float_as_int(Iv.z); nqx=Xv.z; nqy=Yv.z; nqz=Zv.z; }
    if (Vv.y == bm) { fi=__float_as_int(Iv.y); nqx=Xv.y; nqy=Yv.y; nqz=Zv.y; }
    if (Vv.x == bm) { fi=__float_as_int(Iv.x); nqx=Xv.x; nqy=Yv.x; nqz=Zv.x; }
    if (t == 0) sidx[sel] = fi;
    // fused min-update + local max (exact numpy arithmetic)
    m = -INFINITY;
    #pragma unroll
    for (int i=0;i<8;i++) {
      const float d = d2nf(X[i]-nqx, Y[i]-nqy, Z[i]-nqz);
      Mv[i] = fminf(Mv[i], d);
      m = fmaxf(m, Mv[i]);
    }
  }
  __syncthreads();
  for (int j = t; j < Mc; j += 256) idx_ws[b*Mc + j] = sidx[j];  // one coalesced flush
}

// ---------------- Kernel 2: ball query (first-K by index) — round-2 proven version ----------------
// (Round-3's DPP-scan variant had wrong row masks -> holes in nbr[] -> poison-index
//  gather -> GPU memory fault. This LDS Hillis-Steele version is verified correct
//  and costs ~nothing; do not re-optimize without a verified scan.)
__global__ __launch_bounds__(256) void k_ball(const float* __restrict__ pos,
                                              const int* __restrict__ idx_ws,
                                              int* __restrict__ nbr, int* __restrict__ cntarr,
                                              float* __restrict__ q_ws, int* __restrict__ cnt_total,
                                              float* __restrict__ out_pos, float* __restrict__ out_batch,
                                              float* __restrict__ out_idx) {
  __shared__ int sc[256];
  const int g = blockIdx.x, t = threadIdx.x;
  const int b = g >> 10;
  const int li = idx_ws[g];
  const float* pb = pos + (size_t)b*Nc*3;
  const float qx = pb[li*3+0], qy = pb[li*3+1], qz = pb[li*3+2];
  const int base = t*8;
  unsigned mask = 0;
  #pragma unroll
  for (int i=0;i<8;i++){
    const int j = base+i;
    const float d = d2nf(pb[j*3+0]-qx, pb[j*3+1]-qy, pb[j*3+2]-qz);
    if (d <= R2c) mask |= (1u<<i);
  }
  const int c = __popc(mask);
  sc[t] = c; __syncthreads();
  for (int off=1; off<256; off<<=1) {       // inclusive Hillis-Steele scan
    const int add = (t>=off) ? sc[t-off] : 0;
    __syncthreads();
    sc[t] += add;
    __syncthreads();
  }
  const int total = sc[255];
  int slot = sc[t] - c;                      // exclusive prefix
  #pragma unroll
  for (int i=0;i<8;i++){
    if (mask & (1u<<i)) {
      if (slot < Kc) nbr[(size_t)g*Kc + slot] = base+i;
      slot++;
    }
  }
  if (t == 0) {
    const int cv = total < Kc ? total : Kc;
    cntarr[g] = cv;
    atomicAdd(cnt_total, cv);
    q_ws[g*4+0]=qx; q_ws[g*4+1]=qy; q_ws[g*4+2]=qz;
    out_pos[g*3+0]=qx; out_pos[g*3+1]=qy; out_pos[g*3+2]=qz;
    out_batch[g] = (float)b;
    out_idx[g]   = (float)(b*Nc + li);
  }
}

// ---------------- Kernel 3: layer1 stats only (r1 recomputed later; no 134MB spill) ----------------
__global__ __launch_bounds__(256) void k_l1stats(const float* __restrict__ x, const float* __restrict__ pos,
                                                 const float* __restrict__ W1, const float* __restrict__ b1,
                                                 const int* __restrict__ nbr, const int* __restrict__ cntarr,
                                                 const float* __restrict__ q_ws,
                                                 float* __restrict__ p1sum, float* __restrict__ p1sq) {
  __shared__ __align__(16) float inb[Kc][68];
  __shared__ float sred[C1c], sqred[C1c];
  const int t = threadIdx.x;
  const int c0 = (t & 15) * 4, kg = t >> 4;    // thread computes k = kg*4+j, c = c0..c0+3
  const float4 b1q = *(const float4*)(b1 + c0);
  float ssum0=0,ssum1=0,ssum2=0,ssum3=0, ssq0=0,ssq1=0,ssq2=0,ssq3=0;
  const int gk = t >> 2, gq = t & 3;
  for (int gi = 0; gi < GPB; gi++) {
    const int g = blockIdx.x * GPB + gi;
    const int cnt = cntarr[g];
    const int b = g >> 10;
    {   // gather into LDS [64][68]
      float4* dst = (float4*)(&inb[gk][0]);
      if (gk < cnt) {
        const int idx = nbr[(size_t)g*Kc + gk];
        const float4* xr = (const float4*)(x + ((size_t)b*Nc + idx)*Fc);
        #pragma unroll
        for (int ii=0; ii<4; ii++) dst[gq*4+ii] = xr[gq*4+ii];
        if (gq == 0) {
          const float* pp = pos + ((size_t)b*Nc + idx)*3;
          inb[gk][64] = pp[0] - q_ws[g*4+0];
          inb[gk][65] = pp[1] - q_ws[g*4+1];
          inb[gk][66] = pp[2] - q_ws[g*4+2];
          inb[gk][67] = 0.f;
        }
      } else {
        const float4 z4 = make_float4(0.f,0.f,0.f,0.f);
        #pragma unroll
        for (int ii=0; ii<4; ii++) dst[gq*4+ii] = z4;
        if (gq == 0) { inb[gk][64]=0.f; inb[gk][65]=0.f; inb[gk][66]=0.f; inb[gk][67]=0.f; }
      }
    }
    __syncthreads();
    float acc[4][4];
    #pragma unroll
    for (int j=0;j<4;j++){acc[j][0]=0.f;acc[j][1]=0.f;acc[j][2]=0.f;acc[j][3]=0.f;}
    for (int cc=0; cc<C0c; cc++) {
      const float4 w = *(const float4*)(W1 + cc*C1c + c0);
      #pragma unroll
      for (int j=0;j<4;j++) {
        const float hv = inb[kg*4 + j][cc];
        acc[j][0] = fmaf(hv, w.x, acc[j][0]);
        acc[j][1] = fmaf(hv, w.y, acc[j][1]);
        acc[j][2] = fmaf(hv, w.z, acc[j][2]);
        acc[j][3] = fmaf(hv, w.w, acc[j][3]);
      }
    }
    #pragma unroll
    for (int j=0;j<4;j++) {
      const int k = kg*4 + j;
      if (k < cnt) {
        const float r0 = fmaxf(acc[j][0] + b1q.x, 0.f);
        const float r1 = fmaxf(acc[j][1] + b1q.y, 0.f);
        const float r2 = fmaxf(acc[j][2] + b1q.z, 0.f);
        const float r3 = fmaxf(acc[j][3] + b1q.w, 0.f);
        ssum0 += r0; ssq0 += r0*r0;
        ssum1 += r1; ssq1 += r1*r1;
        ssum2 += r2; ssq2 += r2*r2;
        ssum3 += r3; ssq3 += r3*r3;
      }
    }
    __syncthreads();
  }
  if (t < C1c) { sred[t]=0.f; sqred[t]=0.f; }
  __syncthreads();
  atomicAdd(&sred[c0+0], ssum0); atomicAdd(&sqred[c0+0], ssq0);
  atomicAdd(&sred[c0+1], ssum1); atomicAdd(&sqred[c0+1], ssq1);
  atomicAdd(&sred[c0+2], ssum2); atomicAdd(&sqred[c0+2], ssq2);
  atomicAdd(&sred[c0+3], ssum3); atomicAdd(&sqred[c0+3], ssq3);
  __syncthreads();
  if (t < C1c) { p1sum[(size_t)blockIdx.x*C1c + t] = sred[t]; p1sq[(size_t)blockIdx.x*C1c + t] = sqred[t]; }
}

// ---------------- finalize BN stats -> affine (a, c) ----------------
__global__ void k_fin(const float* __restrict__ psum, const float* __restrict__ psq,
                      const int* __restrict__ cnt_total,
                      const float* __restrict__ gam, const float* __restrict__ bet,
                      float* __restrict__ ac, int nch) {
  const int t = threadIdx.x;
  if (t >= nch) return;
  float s = 0.f, sq = 0.f;
  for (int p = 0; p < NBLK; p++) { s += psum[(size_t)p*nch + t]; sq += psq[(size_t)p*nch + t]; }
  const float cntf = (float)(*cnt_total);
  const float mean = s / cntf;
  const float var = fmaxf(sq / cntf - mean*mean, 0.f);
  const float a = gam[t] / sqrtf(var + EPSc);
  ac[t] = a;
  ac[nch + t] = bet[t] - mean * a;
}

// ---------------- Kernel 5: recompute r1, BN1-affine, layer2, masked max/min + stats2 ----------------
__global__ __launch_bounds__(256) void k_l2(const float* __restrict__ x, const float* __restrict__ pos,
                                            const float* __restrict__ W1, const float* __restrict__ b1,
                                            const float* __restrict__ W2, const float* __restrict__ b2,
                                            const int* __restrict__ nbr, const int* __restrict__ cntarr,
                                            const float* __restrict__ q_ws, const float* __restrict__ a1c,
                                            float* __restrict__ p2sum, float* __restrict__ p2sq,
                                            float* __restrict__ maxv, float* __restrict__ minv) {
  __shared__ __align__(16) float inb[Kc][68];
  __shared__ __align__(16) float h1b[Kc][68];
  __shared__ float redmax[8][C2c];
  __shared__ float redmin[8][C2c];
  __shared__ float sred[C2c], sqred[C2c];
  const int t = threadIdx.x;
  const int c0a = (t & 15) * 4, kga = t >> 4;   // phase A: k = kga*4+j
  const int c0b = (t & 31) * 4, kgb = t >> 5;   // phase B: k = kgb*8+j
  const float4 b1q = *(const float4*)(b1 + c0a);
  const float4 a1q = *(const float4*)(a1c + c0a);
  const float4 c1q = *(const float4*)(a1c + C1c + c0a);
  const float4 b2q = *(const float4*)(b2 + c0b);
  float ssum0=0,ssum1=0,ssum2=0,ssum3=0, ssq0=0,ssq1=0,ssq2=0,ssq3=0;
  const int gk = t >> 2, gq = t & 3;
  for (int gi = 0; gi < GPB; gi++) {
    const int g = blockIdx.x * GPB + gi;
    const int cnt = cntarr[g];
    const int b = g >> 10;
    {   // gather
      float4* dst = (float4*)(&inb[gk][0]);
      if (gk < cnt) {
        const int idx = nbr[(size_t)g*Kc + gk];
        const float4* xr = (const float4*)(x + ((size_t)b*Nc + idx)*Fc);
        #pragma unroll
        for (int ii=0; ii<4; ii++) dst[gq*4+ii] = xr[gq*4+ii];
        if (gq == 0) {
          const float* pp = pos + ((size_t)b*Nc + idx)*3;
          inb[gk][64] = pp[0] - q_ws[g*4+0];
          inb[gk][65] = pp[1] - q_ws[g*4+1];
          inb[gk][66] = pp[2] - q_ws[g*4+2];
          inb[gk][67] = 0.f;
        }
      } else {
        const float4 z4 = make_float4(0.f,0.f,0.f,0.f);
        #pragma unroll
        for (int ii=0; ii<4; ii++) dst[gq*4+ii] = z4;
        if (gq == 0) { inb[gk][64]=0.f; inb[gk][65]=0.f; inb[gk][66]=0.f; inb[gk][67]=0.f; }
      }
    }
    __syncthreads();
    {   // phase A: h1 = a1*relu(in@W1+b1)+c1 -> LDS
      float acc[4][4];
      #pragma unroll
      for (int j=0;j<4;j++){acc[j][0]=0.f;acc[j][1]=0.f;acc[j][2]=0.f;acc[j][3]=0.f;}
      for (int cc=0; cc<C0c; cc++) {
        const float4 w = *(const float4*)(W1 + cc*C1c + c0a);
        #pragma unroll
        for (int j=0;j<4;j++) {
          const float hv = inb[kga*4 + j][cc];
          acc[j][0] = fmaf(hv, w.x, acc[j][0]);
          acc[j][1] = fmaf(hv, w.y, acc[j][1]);
          acc[j][2] = fmaf(hv, w.z, acc[j][2]);
          acc[j][3] = fmaf(hv, w.w, acc[j][3]);
        }
      }
      #pragma unroll
      for (int j=0;j<4;j++) {
        const int k = kga*4 + j;
        float4 h;
        h.x = a1q.x * fmaxf(acc[j][0] + b1q.x, 0.f) + c1q.x;
        h.y = a1q.y * fmaxf(acc[j][1] + b1q.y, 0.f) + c1q.y;
        h.z = a1q.z * fmaxf(acc[j][2] + b1q.z, 0.f) + c1q.z;
        h.w = a1q.w * fmaxf(acc[j][3] + b1q.w, 0.f) + c1q.w;
        *(float4*)(&h1b[k][c0a]) = h;
      }
    }
    __syncthreads();
    {   // phase B: r2 = relu(h1@W2+b2); masked stats + max/min over k
      float acc[8][4];
      #pragma unroll
      for (int j=0;j<8;j++){acc[j][0]=0.f;acc[j][1]=0.f;acc[j][2]=0.f;acc[j][3]=0.f;}
      for (int cc=0; cc<C1c; cc++) {
        const float4 w = *(const float4*)(W2 + cc*C2c + c0b);
        #pragma unroll
        for (int j=0;j<8;j++) {
          const float hv = h1b[kgb*8 + j][cc];
          acc[j][0] = fmaf(hv, w.x, acc[j][0]);
          acc[j][1] = fmaf(hv, w.y, acc[j][1]);
          acc[j][2] = fmaf(hv, w.z, acc[j][2]);
          acc[j][3] = fmaf(hv, w.w, acc[j][3]);
        }
      }
      float lx0=-INFINITY,lx1=-INFINITY,lx2=-INFINITY,lx3=-INFINITY;
      float ln0= INFINITY,ln1= INFINITY,ln2= INFINITY,ln3= INFINITY;
      #pragma unroll
      for (int j=0;j<8;j++) {
        const int k = kgb*8 + j;
        if (k < cnt) {
          const float r0 = fmaxf(acc[j][0] + b2q.x, 0.f);
          const float r1 = fmaxf(acc[j][1] + b2q.y, 0.f);
          const float r2 = fmaxf(acc[j][2] + b2q.z, 0.f);
          const float r3 = fmaxf(acc[j][3] + b2q.w, 0.f);
          ssum0 += r0; ssq0 += r0*r0;
          ssum1 += r1; ssq1 += r1*r1;
          ssum2 += r2; ssq2 += r2*r2;
          ssum3 += r3; ssq3 += r3*r3;
          lx0 = fmaxf(lx0, r0); ln0 = fminf(ln0, r0);
          lx1 = fmaxf(lx1, r1); ln1 = fminf(ln1, r1);
          lx2 = fmaxf(lx2, r2); ln2 = fminf(ln2, r2);
          lx3 = fmaxf(lx3, r3); ln3 = fminf(ln3, r3);
        }
      }
      redmax[kgb][c0b+0]=lx0; redmax[kgb][c0b+1]=lx1; redmax[kgb][c0b+2]=lx2; redmax[kgb][c0b+3]=lx3;
      redmin[kgb][c0b+0]=ln0; redmin[kgb][c0b+1]=ln1; redmin[kgb][c0b+2]=ln2; redmin[kgb][c0b+3]=ln3;
    }
    __syncthreads();
    if (t < C2c) {
      float mx = redmax[0][t], mn = redmin[0][t];
      #pragma unroll
      for (int w=1; w<8; w++) { mx = fmaxf(mx, redmax[w][t]); mn = fminf(mn, redmin[w][t]); }
      maxv[(size_t)g*C2c + t] = mx;
      minv[(size_t)g*C2c + t] = mn;
    }
    __syncthreads();
  }
  if (t < C2c) { sred[t] = 0.f; sqred[t] = 0.f; }
  __syncthreads();
  atomicAdd(&sred[c0b+0], ssum0); atomicAdd(&sqred[c0b+0], ssq0);
  atomicAdd(&sred[c0b+1], ssum1); atomicAdd(&sqred[c0b+1], ssq1);
  atomicAdd(&sred[c0b+2], ssum2); atomicAdd(&sqred[c0b+2], ssq2);
  atomicAdd(&sred[c0b+3], ssum3); atomicAdd(&sqred[c0b+3], ssq3);
  __syncthreads();
  if (t < C2c) { p2sum[(size_t)blockIdx.x*C2c + t] = sred[t]; p2sq[(size_t)blockIdx.x*C2c + t] = sqred[t]; }
}

// ---------------- Kernel 7: x_out = a2*extreme + c2 (BN2 commutes with masked max) ----------------
__global__ __launch_bounds__(256) void k_out(const float* __restrict__ maxv, const float* __restrict__ minv,
                                             const float* __restrict__ a2c, float* __restrict__ xout) {
  const int i = blockIdx.x*256 + threadIdx.x;
  const int c = i & (C2c-1);
  const float a = a2c[c], cc = a2c[C2c + c];
  const float v = (a >= 0.f) ? maxv[i] : minv[i];
  xout[i] = a * v + cc;
}

extern "C" void kernel_launch(void* const* d_in, const int* in_sizes, int n_in,
                              void* d_out, int out_size, void* d_ws, size_t ws_size,
                              hipStream_t stream) {
  (void)in_sizes; (void)n_in; (void)out_size; (void)ws_size;
  const float* x   = (const float*)d_in[0];
  const float* pos = (const float*)d_in[1];
  const float* W1  = (const float*)d_in[3];
  const float* b1  = (const float*)d_in[4];
  const float* g1  = (const float*)d_in[5];
  const float* be1 = (const float*)d_in[6];
  const float* W2  = (const float*)d_in[7];
  const float* b2  = (const float*)d_in[8];
  const float* g2  = (const float*)d_in[9];
  const float* be2 = (const float*)d_in[10];

  char* ws = (char*)d_ws;                      // ~11.5 MB total
  int*   idx_ws    = (int*)  (ws + 0);         // [8192]
  int*   cntarr    = (int*)  (ws + 32768);     // [8192]
  int*   nbr       = (int*)  (ws + 65536);     // [8192*64]
  float* q_ws      = (float*)(ws + 2162688);   // [8192*4]
  int*   cnt_total = (int*)  (ws + 2293760);
  float* p1sum     = (float*)(ws + 2294016);   // [512*64]
  float* p1sq      = (float*)(ws + 2425088);
  float* p2sum     = (float*)(ws + 2556160);   // [512*128]
  float* p2sq      = (float*)(ws + 2818304);
  float* a1c       = (float*)(ws + 3080448);   // [128]
  float* a2c       = (float*)(ws + 3080960);   // [256]
  float* maxv      = (float*)(ws + 3081984);   // [8192*128]
  float* minv      = (float*)(ws + 7276288);   // [8192*128]

  float* xout      = (float*)d_out;            // [8192*128]
  float* out_pos   = xout + (size_t)NGRP*C2c;  // [8192*3]
  float* out_batch = out_pos + (size_t)NGRP*3; // [8192]
  float* out_idx   = out_batch + NGRP;         // [8192]

  k_fps<<<Bc, 256, 0, stream>>>(pos, idx_ws, cnt_total);
  k_ball<<<NGRP, 256, 0, stream>>>(pos, idx_ws, nbr, cntarr, q_ws, cnt_total,
                                   out_pos, out_batch, out_idx);
  k_l1stats<<<NBLK, 256, 0, stream>>>(x, pos, W1, b1, nbr, cntarr, q_ws, p1sum, p1sq);
  k_fin<<<1, C1c, 0, stream>>>(p1sum, p1sq, cnt_total, g1, be1, a1c, C1c);
  k_l2<<<NBLK, 256, 0, stream>>>(x, pos, W1, b1, W2, b2, nbr, cntarr, q_ws, a1c,
                                 p2sum, p2sq, maxv, minv);
  k_fin<<<1, C2c, 0, stream>>>(p2sum, p2sq, cnt_total, g2, be2, a2c, C2c);
  k_out<<<(NGRP*C2c)/256, 256, 0, stream>>>(maxv, minv, a2c, xout);
}